// Round 1
// baseline (537.999 us; speedup 1.0000x reference)
//
#include <hip/hip_runtime.h>

#define B_   8
#define H_   112
#define W_   112
#define HW_  12544
#define C_   128
#define NH_  4
#define HD_  32
#define KK_  49
#define N_   100352
#define SCALE_ 0.17677669529663687f   // 1/sqrt(32)

// ---------------- K1: QKV GEMM + per-pixel q.k dot + v store ----------------
// grid = N_/64 = 1568 blocks, 256 threads. Each block: 64 consecutive pixels
// (never crosses batch: HW_/64 = 196 exact). og = tid>>6 in [0,4) = head;
// each og-wave computes that head's 32 q, 32 k, 32 v channels for its pixel.
// Weight reads are wave-uniform -> scalar loads (readfirstlane forces SGPR og).

__device__ __forceinline__ void gemm_pass32(
    const float* __restrict__ w, const float* __restrict__ bias,
    const float* __restrict__ xcol, float* __restrict__ acc)
{
#pragma unroll
  for (int t = 0; t < 32; ++t) acc[t] = bias[t];
#pragma unroll 2
  for (int c = 0; c < C_; ++c) {
    const float xv = xcol[c * 64];   // lane=px -> 2 lanes/bank: free
#pragma unroll
    for (int t = 0; t < 32; ++t) acc[t] = fmaf(xv, w[t * C_ + c], acc[t]);
  }
}

__global__ __launch_bounds__(256) void k_qkv(
    const float* __restrict__ x, const float* __restrict__ qw,
    const float* __restrict__ qb, float* __restrict__ vbuf,
    float* __restrict__ dotbuf)
{
  __shared__ __align__(16) float xs[C_ * 64];   // [c][px], 32 KB
  const int tid = threadIdx.x;
  const int b   = blockIdx.x / (HW_ / 64);
  const int hw0 = (blockIdx.x % (HW_ / 64)) * 64;

  { // stage x tile: per c, 64 contiguous floats (coalesced float4)
    const float* xb = x + (size_t)b * C_ * HW_ + hw0;
    const int p4 = (tid & 15) * 4;
    const int c0 = tid >> 4;
#pragma unroll
    for (int rep = 0; rep < 8; ++rep) {
      const int c = c0 + rep * 16;
      const float4 v = *(const float4*)(xb + (size_t)c * HW_ + p4);
      *(float4*)(xs + c * 64 + p4) = v;
    }
  }
  __syncthreads();

  const int px = tid & 63;
  const int og = __builtin_amdgcn_readfirstlane((int)threadIdx.x >> 6);
  const float* xcol = xs + px;

  float accq[32], acck[32];
  gemm_pass32(qw + (size_t)(og * HD_) * C_,            qb + og * HD_,            xcol, accq);
  gemm_pass32(qw + (size_t)(C_ + og * HD_) * C_,       qb + C_ + og * HD_,       xcol, acck);

  float d = 0.f;
#pragma unroll
  for (int t = 0; t < 32; ++t) d = fmaf(accq[t], acck[t], d);
  dotbuf[(size_t)(b * NH_ + og) * HW_ + hw0 + px] = d * SCALE_;

  float accv[32];
  gemm_pass32(qw + (size_t)(2 * C_ + og * HD_) * C_,   qb + 2 * C_ + og * HD_,   xcol, accv);

  // v layout: (B, NH, HW, HD) head-major for K2's per-head tiles.
  // Lane writes 8x float4 at 128B lane stride: region fully covered -> L2 merges.
  float* vout = vbuf + ((size_t)(b * NH_ + og) * HW_ + hw0 + px) * HD_;
#pragma unroll
  for (int t = 0; t < 32; t += 4)
    *(float4*)(vout + t) = make_float4(accv[t], accv[t+1], accv[t+2], accv[t+3]);
}

// ---------------- K2: neighborhood softmax + A*V ----------------
// grid = NH_*B_*7*7 = 1568 blocks (one head, one 16x16 pixel tile), 256 thr.
// Phase A: one softmax per thread -> normalized-later exp table at[off][px].
// Phase B: thread = (row r, half sx, c4): 8 out pixels x 4 channels, sliding
// 14-float4 v window per row i reused across 7 j-offsets.

__global__ __launch_bounds__(256) void k_attn(
    const float* __restrict__ vbuf, const float* __restrict__ dotbuf,
    const float* __restrict__ rpb, float* __restrict__ abuf)
{
  __shared__ __align__(16) float at[KK_ * 256];  // [off][px], 50 KB
  __shared__ float rsum[256];
  const int tid  = threadIdx.x;
  const int blk  = blockIdx.x;
  const int head = blk / 392;
  const int rem  = blk % 392;
  const int b    = rem / 49;
  const int t49  = rem % 49;
  const int r0 = (t49 / 7) * 16;
  const int w0 = (t49 % 7) * 16;
  const float* dptr = dotbuf + (size_t)(b * NH_ + head) * HW_;

  { // phase A: softmax logits = dot[(h+i)%112][(w+j)%112] + rpb[head,i,j]
    const int r = tid >> 4, wv = tid & 15;
    const int gh = r0 + r, gw = w0 + wv;
    float logit[KK_];
    float m = -1e30f;
#pragma unroll
    for (int i = 0; i < 7; ++i) {
      int hr = gh + i; if (hr >= H_) hr -= H_;
      const float* drow = dptr + hr * W_;
#pragma unroll
      for (int j = 0; j < 7; ++j) {
        int wc = gw + j; if (wc >= W_) wc -= W_;
        const float l = drow[wc] + rpb[head * KK_ + i * 7 + j];
        logit[i * 7 + j] = l;
        m = fmaxf(m, l);
      }
    }
    float s = 0.f;
#pragma unroll
    for (int o = 0; o < KK_; ++o) {
      const float e = __expf(logit[o] - m);
      s += e;
      at[o * 256 + tid] = e;   // lanes contiguous: conflict-free
    }
    rsum[tid] = 1.0f / s;
  }
  __syncthreads();

  const int c4  = tid & 7;
  const int seg = tid >> 3;
  const int r   = seg >> 1;
  const int sx  = (seg & 1) * 8;
  const int gh  = r0 + r;
  const int pxb = r * 16 + sx;               // multiple of 8 -> 16B-aligned at[] reads
  const float* vb = vbuf + (size_t)(b * NH_ + head) * HW_ * HD_ + c4 * 4;

  float4 acc[8];
#pragma unroll
  for (int xx = 0; xx < 8; ++xx) acc[xx] = make_float4(0.f, 0.f, 0.f, 0.f);

  for (int i = 0; i < 7; ++i) {
    int hr = gh + i; if (hr >= H_) hr -= H_;
    float4 win[14];
#pragma unroll
    for (int t = 0; t < 14; ++t) {
      int wc = w0 + sx + t; if (wc >= W_) wc -= W_;
      win[t] = *(const float4*)(vb + ((size_t)hr * W_ + wc) * HD_);
    }
#pragma unroll
    for (int j = 0; j < 7; ++j) {
      const float* arow = at + (i * 7 + j) * 256 + pxb;
      const float4 a0 = *(const float4*)arow;
      const float4 a1 = *(const float4*)(arow + 4);
      const float aw[8] = {a0.x, a0.y, a0.z, a0.w, a1.x, a1.y, a1.z, a1.w};
#pragma unroll
      for (int xx = 0; xx < 8; ++xx) {
        acc[xx].x = fmaf(aw[xx], win[xx + j].x, acc[xx].x);
        acc[xx].y = fmaf(aw[xx], win[xx + j].y, acc[xx].y);
        acc[xx].z = fmaf(aw[xx], win[xx + j].z, acc[xx].z);
        acc[xx].w = fmaf(aw[xx], win[xx + j].w, acc[xx].w);
      }
    }
  }

  // abuf layout: (B, HW, C) pixel-major; this block covers channels [head*32, +32)
  float* op = abuf + ((size_t)b * HW_ + (size_t)gh * W_ + (w0 + sx)) * C_ + head * HD_ + c4 * 4;
#pragma unroll
  for (int xx = 0; xx < 8; ++xx) {
    const float rs = rsum[pxb + xx];
    *(float4*)(op + xx * C_) =
        make_float4(acc[xx].x * rs, acc[xx].y * rs, acc[xx].z * rs, acc[xx].w * rs);
  }
}

// ---------------- K3: proj GEMM + NHWC -> NCHW ----------------
// grid = 1568 blocks of 64 pixels, 256 threads. ys stride 129 (odd) ->
// lane=px GEMM reads are bank-conflict-free. Output stores coalesced per o.
__global__ __launch_bounds__(256) void k_proj(
    const float* __restrict__ abuf, const float* __restrict__ pw,
    const float* __restrict__ pb, float* __restrict__ out)
{
  __shared__ float ys[64 * 129];   // [px][c] padded, 33 KB
  const int tid = threadIdx.x;
  const int b   = blockIdx.x / 196;
  const int hw0 = (blockIdx.x % 196) * 64;
  {
    const float* ab = abuf + ((size_t)b * HW_ + hw0) * C_;
#pragma unroll
    for (int rep = 0; rep < 8; ++rep) {
      const int f4i = rep * 256 + tid;
      const int p  = f4i >> 5;
      const int cc = (f4i & 31) * 4;
      const float4 v = *(const float4*)(ab + p * C_ + cc);
      float* dst = ys + p * 129 + cc;
      dst[0] = v.x; dst[1] = v.y; dst[2] = v.z; dst[3] = v.w;
    }
  }
  __syncthreads();

  const int px = tid & 63;
  const int og = __builtin_amdgcn_readfirstlane((int)threadIdx.x >> 6);
  const float* yrow = ys + px * 129;
  const float* w = pw + (size_t)og * 32 * C_;
  float acc[32];
#pragma unroll
  for (int t = 0; t < 32; ++t) acc[t] = pb[og * 32 + t];
#pragma unroll 2
  for (int c = 0; c < C_; ++c) {
    const float xv = yrow[c];
#pragma unroll
    for (int t = 0; t < 32; ++t) acc[t] = fmaf(xv, w[t * C_ + c], acc[t]);
  }
  float* o = out + (size_t)b * C_ * HW_ + (size_t)og * 32 * HW_ + hw0 + px;
#pragma unroll
  for (int t = 0; t < 32; ++t) o[(size_t)t * HW_] = acc[t];   // lanes=px coalesced
}

extern "C" void kernel_launch(void* const* d_in, const int* in_sizes, int n_in,
                              void* d_out, int out_size, void* d_ws, size_t ws_size,
                              hipStream_t stream) {
  const float* x   = (const float*)d_in[0];
  const float* qw  = (const float*)d_in[1];
  const float* qb  = (const float*)d_in[2];
  const float* rpb = (const float*)d_in[3];
  const float* pw  = (const float*)d_in[4];
  const float* pb  = (const float*)d_in[5];
  float* out = (float*)d_out;

  float* vbuf = (float*)d_ws;                         // N_*C_ floats (51.4 MB)
  float* dotb = vbuf + (size_t)N_ * C_;               // N_*NH_ floats (1.6 MB)
  float* abuf = dotb + (size_t)N_ * NH_;              // N_*C_ floats (51.4 MB)

  hipLaunchKernelGGL(k_qkv,  dim3(N_ / 64), dim3(256), 0, stream, x, qw, qb, vbuf, dotb);
  hipLaunchKernelGGL(k_attn, dim3(NH_ * B_ * 49), dim3(256), 0, stream, vbuf, dotb, rpb, abuf);
  hipLaunchKernelGGL(k_proj, dim3(N_ / 64), dim3(256), 0, stream, abuf, pw, pb, out);
}

// Round 2
// 355.331 us; speedup vs baseline: 1.5141x; 1.5141x over previous
//
#include <hip/hip_runtime.h>

#define B_   8
#define H_   112
#define W_   112
#define HW_  12544
#define C_   128
#define NH_  4
#define HD_  32
#define KK_  49
#define N_   100352
#define SCALE_ 0.17677669529663687f   // 1/sqrt(32)

// ---------------- K0: transpose weights so per-c rows are contiguous --------
// qkv_w (384x128) -> wt[c][oc] (128x384); proj_w (128x128) -> pwt[c][oc].
// Makes the GEMM kernels' wave-uniform weight reads contiguous 128B ->
// s_load_dwordx16 instead of 32 scattered s_load_dword (K$ thrash fix).
__global__ __launch_bounds__(256) void k_wt(
    const float* __restrict__ qw, const float* __restrict__ pw,
    float* __restrict__ wt, float* __restrict__ pwt)
{
  const int idx = blockIdx.x * 256 + threadIdx.x;
  if (idx < 384 * 128) {
    const int r = idx >> 7, c = idx & 127;
    wt[c * 384 + r] = qw[idx];
  }
  if (idx < 128 * 128) {
    const int r = idx >> 7, c = idx & 127;
    pwt[c * 128 + r] = pw[idx];
  }
}

// ---------------- K1: QKV GEMM + per-pixel q.k dot + v store ----------------
// 64 px/block, 256 threads, og = wave = head. Weights via contiguous
// wave-uniform scalar loads from the transposed copy.

template <int LDW>
__device__ __forceinline__ void gemm_pass32_t(
    const float* __restrict__ w,      // pre-offset to this wave's 32 oc
    const float* __restrict__ bias, const float* __restrict__ xcol,
    float* __restrict__ acc)
{
#pragma unroll
  for (int t = 0; t < 32; ++t) acc[t] = bias[t];
#pragma unroll 2
  for (int c = 0; c < C_; ++c) {
    const float xv = xcol[c * 64];    // lane=px, 2 lanes/bank: free
    const float* __restrict__ wr = w + c * LDW;
#pragma unroll
    for (int t = 0; t < 32; ++t) acc[t] = fmaf(xv, wr[t], acc[t]);
  }
}

__global__ __launch_bounds__(256) void k_qkv(
    const float* __restrict__ x, const float* __restrict__ wt,
    const float* __restrict__ qb, float* __restrict__ vbuf,
    float* __restrict__ dotbuf)
{
  __shared__ __align__(16) float xs[C_ * 64];   // [c][px], 32 KB
  const int tid = threadIdx.x;
  const int b   = blockIdx.x / (HW_ / 64);
  const int hw0 = (blockIdx.x % (HW_ / 64)) * 64;

  { // stage x tile: per c, 64 contiguous floats (coalesced float4)
    const float* xb = x + (size_t)b * C_ * HW_ + hw0;
    const int p4 = (tid & 15) * 4;
    const int c0 = tid >> 4;
#pragma unroll
    for (int rep = 0; rep < 8; ++rep) {
      const int c = c0 + rep * 16;
      const float4 v = *(const float4*)(xb + (size_t)c * HW_ + p4);
      *(float4*)(xs + c * 64 + p4) = v;
    }
  }
  __syncthreads();

  const int px = tid & 63;
  const int og = __builtin_amdgcn_readfirstlane((int)threadIdx.x >> 6);
  const float* xcol = xs + px;

  float accq[32], acck[32];
  gemm_pass32_t<384>(wt + og * HD_,        qb + og * HD_,        xcol, accq);
  gemm_pass32_t<384>(wt + C_ + og * HD_,   qb + C_ + og * HD_,   xcol, acck);

  float d = 0.f;
#pragma unroll
  for (int t = 0; t < 32; ++t) d = fmaf(accq[t], acck[t], d);
  dotbuf[(size_t)(b * NH_ + og) * HW_ + hw0 + px] = d * SCALE_;

  float accv[32];
  gemm_pass32_t<384>(wt + 2 * C_ + og * HD_, qb + 2 * C_ + og * HD_, xcol, accv);

  // v layout: (B, NH, HW, HD) head-major for K2's per-head tiles.
  float* vout = vbuf + ((size_t)(b * NH_ + og) * HW_ + hw0 + px) * HD_;
#pragma unroll
  for (int t = 0; t < 32; t += 4)
    *(float4*)(vout + t) = make_float4(accv[t], accv[t+1], accv[t+2], accv[t+3]);
}

// ---------------- K2: neighborhood softmax + A*V ----------------
__global__ __launch_bounds__(256) void k_attn(
    const float* __restrict__ vbuf, const float* __restrict__ dotbuf,
    const float* __restrict__ rpb, float* __restrict__ abuf)
{
  __shared__ __align__(16) float at[KK_ * 256];  // [off][px], 50 KB
  __shared__ float rsum[256];
  const int tid  = threadIdx.x;
  const int blk  = blockIdx.x;
  const int head = blk / 392;
  const int rem  = blk % 392;
  const int b    = rem / 49;
  const int t49  = rem % 49;
  const int r0 = (t49 / 7) * 16;
  const int w0 = (t49 % 7) * 16;
  const float* dptr = dotbuf + (size_t)(b * NH_ + head) * HW_;

  { // phase A: softmax logits = dot[(h+i)%112][(w+j)%112] + rpb[head,i,j]
    const int r = tid >> 4, wv = tid & 15;
    const int gh = r0 + r, gw = w0 + wv;
    float logit[KK_];
    float m = -1e30f;
#pragma unroll
    for (int i = 0; i < 7; ++i) {
      int hr = gh + i; if (hr >= H_) hr -= H_;
      const float* drow = dptr + hr * W_;
#pragma unroll
      for (int j = 0; j < 7; ++j) {
        int wc = gw + j; if (wc >= W_) wc -= W_;
        const float l = drow[wc] + rpb[head * KK_ + i * 7 + j];
        logit[i * 7 + j] = l;
        m = fmaxf(m, l);
      }
    }
    float s = 0.f;
#pragma unroll
    for (int o = 0; o < KK_; ++o) {
      const float e = __expf(logit[o] - m);
      s += e;
      at[o * 256 + tid] = e;   // lanes contiguous: conflict-free
    }
    rsum[tid] = 1.0f / s;
  }
  __syncthreads();

  const int c4  = tid & 7;
  const int seg = tid >> 3;
  const int r   = seg >> 1;
  const int sx  = (seg & 1) * 8;
  const int gh  = r0 + r;
  const int pxb = r * 16 + sx;
  const float* vb = vbuf + (size_t)(b * NH_ + head) * HW_ * HD_ + c4 * 4;

  float4 acc[8];
#pragma unroll
  for (int xx = 0; xx < 8; ++xx) acc[xx] = make_float4(0.f, 0.f, 0.f, 0.f);

  for (int i = 0; i < 7; ++i) {
    int hr = gh + i; if (hr >= H_) hr -= H_;
    float4 win[14];
#pragma unroll
    for (int t = 0; t < 14; ++t) {
      int wc = w0 + sx + t; if (wc >= W_) wc -= W_;
      win[t] = *(const float4*)(vb + ((size_t)hr * W_ + wc) * HD_);
    }
#pragma unroll
    for (int j = 0; j < 7; ++j) {
      const float* arow = at + (i * 7 + j) * 256 + pxb;
      const float4 a0 = *(const float4*)arow;
      const float4 a1 = *(const float4*)(arow + 4);
      const float aw[8] = {a0.x, a0.y, a0.z, a0.w, a1.x, a1.y, a1.z, a1.w};
#pragma unroll
      for (int xx = 0; xx < 8; ++xx) {
        acc[xx].x = fmaf(aw[xx], win[xx + j].x, acc[xx].x);
        acc[xx].y = fmaf(aw[xx], win[xx + j].y, acc[xx].y);
        acc[xx].z = fmaf(aw[xx], win[xx + j].z, acc[xx].z);
        acc[xx].w = fmaf(aw[xx], win[xx + j].w, acc[xx].w);
      }
    }
  }

  float* op = abuf + ((size_t)b * HW_ + (size_t)gh * W_ + (w0 + sx)) * C_ + head * HD_ + c4 * 4;
#pragma unroll
  for (int xx = 0; xx < 8; ++xx) {
    const float rs = rsum[pxb + xx];
    *(float4*)(op + xx * C_) =
        make_float4(acc[xx].x * rs, acc[xx].y * rs, acc[xx].z * rs, acc[xx].w * rs);
  }
}

// ---------------- K3: proj GEMM + NHWC -> NCHW ----------------
__global__ __launch_bounds__(256) void k_proj(
    const float* __restrict__ abuf, const float* __restrict__ pwt,
    const float* __restrict__ pb, float* __restrict__ out)
{
  __shared__ float ys[64 * 129];   // [px][c] padded, 33 KB
  const int tid = threadIdx.x;
  const int b   = blockIdx.x / 196;
  const int hw0 = (blockIdx.x % 196) * 64;
  {
    const float* ab = abuf + ((size_t)b * HW_ + hw0) * C_;
#pragma unroll
    for (int rep = 0; rep < 8; ++rep) {
      const int f4i = rep * 256 + tid;
      const int p  = f4i >> 5;
      const int cc = (f4i & 31) * 4;
      const float4 v = *(const float4*)(ab + p * C_ + cc);
      float* dst = ys + p * 129 + cc;
      dst[0] = v.x; dst[1] = v.y; dst[2] = v.z; dst[3] = v.w;
    }
  }
  __syncthreads();

  const int px = tid & 63;
  const int og = __builtin_amdgcn_readfirstlane((int)threadIdx.x >> 6);
  const float* yrow = ys + px * 129;
  const float* w = pwt + og * HD_;     // pwt[c][oc], reads contiguous 32 oc
  float acc[32];
#pragma unroll
  for (int t = 0; t < 32; ++t) acc[t] = pb[og * 32 + t];
#pragma unroll 2
  for (int c = 0; c < C_; ++c) {
    const float xv = yrow[c];
    const float* __restrict__ wr = w + c * C_;
#pragma unroll
    for (int t = 0; t < 32; ++t) acc[t] = fmaf(xv, wr[t], acc[t]);
  }
  float* o = out + (size_t)b * C_ * HW_ + (size_t)og * 32 * HW_ + hw0 + px;
#pragma unroll
  for (int t = 0; t < 32; ++t) o[(size_t)t * HW_] = acc[t];
}

extern "C" void kernel_launch(void* const* d_in, const int* in_sizes, int n_in,
                              void* d_out, int out_size, void* d_ws, size_t ws_size,
                              hipStream_t stream) {
  const float* x   = (const float*)d_in[0];
  const float* qw  = (const float*)d_in[1];
  const float* qb  = (const float*)d_in[2];
  const float* rpb = (const float*)d_in[3];
  const float* pw  = (const float*)d_in[4];
  const float* pb  = (const float*)d_in[5];
  float* out = (float*)d_out;

  float* vbuf = (float*)d_ws;                         // N_*C_ floats (51.4 MB)
  float* dotb = vbuf + (size_t)N_ * C_;               // N_*NH_ floats (1.6 MB)
  float* abuf = dotb + (size_t)N_ * NH_;              // N_*C_ floats (51.4 MB)
  float* wt   = abuf + (size_t)N_ * C_;               // 128*384 floats
  float* pwt  = wt + 384 * C_;                        // 128*128 floats

  hipLaunchKernelGGL(k_wt,   dim3(192), dim3(256), 0, stream, qw, pw, wt, pwt);
  hipLaunchKernelGGL(k_qkv,  dim3(N_ / 64), dim3(256), 0, stream, x, wt, qb, vbuf, dotb);
  hipLaunchKernelGGL(k_attn, dim3(NH_ * B_ * 49), dim3(256), 0, stream, vbuf, dotb, rpb, abuf);
  hipLaunchKernelGGL(k_proj, dim3(N_ / 64), dim3(256), 0, stream, abuf, pwt, pb, out);
}

// Round 3
// 253.579 us; speedup vs baseline: 2.1216x; 1.4013x over previous
//
#include <hip/hip_runtime.h>

#define B_   8
#define H_   112
#define W_   112
#define HW_  12544
#define C_   128
#define NH_  4
#define HD_  32
#define KK_  49
#define N_   100352
#define SCALE_ 0.17677669529663687f   // 1/sqrt(32)

typedef __attribute__((ext_vector_type(8))) short short8;
typedef __attribute__((ext_vector_type(4))) float floatx4;

__device__ __forceinline__ unsigned short f2bf(float f) {
  unsigned u = __float_as_uint(f);
  return (unsigned short)((u + 0x7fffu + ((u >> 16) & 1u)) >> 16);
}
__device__ __forceinline__ float bf2f(unsigned short h) {
  return __uint_as_float(((unsigned)h) << 16);
}

// ---------------- K0: weight prep ----------------
// qkv_w (384x128 row-major, [oc][c]) -> bf16 hi/lo copies (A-fragment order =
// row-major already). proj_w -> transposed fp32 for the (still-VALU) K3.
__global__ __launch_bounds__(256) void k_wt(
    const float* __restrict__ qw, const float* __restrict__ pw,
    unsigned short* __restrict__ wh, unsigned short* __restrict__ wl,
    float* __restrict__ pwt)
{
  const int idx = blockIdx.x * 256 + threadIdx.x;
  if (idx < 384 * 128) {
    const float v = qw[idx];
    const unsigned short h = f2bf(v);
    wh[idx] = h;
    wl[idx] = f2bf(v - bf2f(h));
  }
  if (idx < 128 * 128) {
    const int r = idx >> 7, c = idx & 127;
    pwt[c * 128 + r] = pw[idx];
  }
}

// ---------------- K1: QKV via split-bf16 MFMA + q.k dot + v store ----------
// Block = 64 px, 4 waves; wave w = head w. Tiles: m=oc (16), n=px (16), K=32.
// Y = (xh+xl)(wh+wl) ~ xh*wh + xh*wl + xl*wh  (3 MFMA per acc per kstep).
// Per wave: 6 oc-tiles (q0,q1,k0,k1,v0,v1 of its head) x 4 px-tiles.
__global__ __launch_bounds__(256, 2) void k_qkv(
    const float* __restrict__ x, const unsigned short* __restrict__ wh,
    const unsigned short* __restrict__ wl, const float* __restrict__ qb,
    float* __restrict__ vbuf, float* __restrict__ dotbuf)
{
  __shared__ __align__(16) float xs[C_ * 64];            // [c][px] fp32, 32 KB
  __shared__ __align__(16) unsigned short xh[64 * 136];  // [px][c] bf16-hi, pad->2-way free
  __shared__ __align__(16) unsigned short xl[64 * 136];  // [px][c] bf16-lo
  const int tid = threadIdx.x;
  const int b   = blockIdx.x / 196;
  const int hw0 = (blockIdx.x % 196) * 64;

  { // stage x tile coalesced
    const float* xb = x + (size_t)b * C_ * HW_ + hw0;
    const int p4 = (tid & 15) * 4;
    const int c0 = tid >> 4;
#pragma unroll
    for (int rep = 0; rep < 8; ++rep) {
      const int c = c0 + rep * 16;
      *(float4*)(xs + c * 64 + p4) = *(const float4*)(xb + (size_t)c * HW_ + p4);
    }
  }
  __syncthreads();

  { // transpose + hi/lo split: thread owns (px, 32 c)
    const int px = tid & 63;
    const int c0 = (tid >> 6) * 32;
#pragma unroll
    for (int cc = 0; cc < 32; cc += 2) {
      const int c = c0 + cc;
      const float f0 = xs[c * 64 + px], f1 = xs[(c + 1) * 64 + px];
      const unsigned short h0 = f2bf(f0), h1 = f2bf(f1);
      const unsigned short l0 = f2bf(f0 - bf2f(h0)), l1 = f2bf(f1 - bf2f(h1));
      *(unsigned*)(xh + px * 136 + c) = (unsigned)h0 | ((unsigned)h1 << 16);
      *(unsigned*)(xl + px * 136 + c) = (unsigned)l0 | ((unsigned)l1 << 16);
    }
  }
  __syncthreads();

  const int w    = __builtin_amdgcn_readfirstlane(tid >> 6);
  const int l    = tid & 63;
  const int m16  = l & 15;
  const int quad = l >> 4;

  int ocbase[6];
#pragma unroll
  for (int g = 0; g < 6; ++g) ocbase[g] = (g >> 1) * 128 + w * 32 + (g & 1) * 16;

  floatx4 acc[6][4];
#pragma unroll
  for (int g = 0; g < 6; ++g)
#pragma unroll
    for (int p = 0; p < 4; ++p) acc[g][p] = (floatx4){0.f, 0.f, 0.f, 0.f};

  for (int ks = 0; ks < 4; ++ks) {
    short8 bh[4], bl[4];
#pragma unroll
    for (int p = 0; p < 4; ++p) {   // B-frags from LDS, reused over 6 oc-tiles
      const int off = (p * 16 + m16) * 136 + ks * 32 + quad * 8;
      bh[p] = *(const short8*)(xh + off);
      bl[p] = *(const short8*)(xl + off);
    }
#pragma unroll
    for (int g = 0; g < 6; ++g) {
      const size_t woff = (size_t)(ocbase[g] + m16) * C_ + ks * 32 + quad * 8;
      const short8 ah = *(const short8*)(wh + woff);
      const short8 al = *(const short8*)(wl + woff);
#pragma unroll
      for (int p = 0; p < 4; ++p) {
        acc[g][p] = __builtin_amdgcn_mfma_f32_16x16x32_bf16(ah, bh[p], acc[g][p], 0, 0, 0);
        acc[g][p] = __builtin_amdgcn_mfma_f32_16x16x32_bf16(ah, bl[p], acc[g][p], 0, 0, 0);
        acc[g][p] = __builtin_amdgcn_mfma_f32_16x16x32_bf16(al, bh[p], acc[g][p], 0, 0, 0);
      }
    }
  }

  // per-lane biases: D row = ocbase[g] + quad*4 + r
  float bias[6][4];
#pragma unroll
  for (int g = 0; g < 6; ++g)
#pragma unroll
    for (int r = 0; r < 4; ++r) bias[g][r] = qb[ocbase[g] + quad * 4 + r];

  const size_t dbase = (size_t)(b * NH_ + w) * HW_ + hw0;

  // dot = scale * sum_oc q*k : in-lane 8 products, then quad reduction
#pragma unroll
  for (int p = 0; p < 4; ++p) {
    float part = 0.f;
#pragma unroll
    for (int t = 0; t < 2; ++t)
#pragma unroll
      for (int r = 0; r < 4; ++r)
        part += (acc[t][p][r] + bias[t][r]) * (acc[2 + t][p][r] + bias[2 + t][r]);
    part += __shfl_xor(part, 16);
    part += __shfl_xor(part, 32);
    if (l < 16) dotbuf[dbase + p * 16 + l] = part * SCALE_;
  }

  // v store: (B, NH, HW, HD) fp32, lane writes float4 at oc = t*16 + quad*4
#pragma unroll
  for (int t = 0; t < 2; ++t) {
#pragma unroll
    for (int p = 0; p < 4; ++p) {
      floatx4 vv = acc[4 + t][p];
#pragma unroll
      for (int r = 0; r < 4; ++r) vv[r] += bias[4 + t][r];
      float* vp = vbuf + (dbase + p * 16 + m16) * HD_ + t * 16 + quad * 4;
      *(floatx4*)vp = vv;
    }
  }
}

// ---------------- K2: neighborhood softmax + A*V (unchanged) ----------------
__global__ __launch_bounds__(256) void k_attn(
    const float* __restrict__ vbuf, const float* __restrict__ dotbuf,
    const float* __restrict__ rpb, float* __restrict__ abuf)
{
  __shared__ __align__(16) float at[KK_ * 256];
  __shared__ float rsum[256];
  const int tid  = threadIdx.x;
  const int blk  = blockIdx.x;
  const int head = blk / 392;
  const int rem  = blk % 392;
  const int b    = rem / 49;
  const int t49  = rem % 49;
  const int r0 = (t49 / 7) * 16;
  const int w0 = (t49 % 7) * 16;
  const float* dptr = dotbuf + (size_t)(b * NH_ + head) * HW_;

  {
    const int r = tid >> 4, wv = tid & 15;
    const int gh = r0 + r, gw = w0 + wv;
    float logit[KK_];
    float m = -1e30f;
#pragma unroll
    for (int i = 0; i < 7; ++i) {
      int hr = gh + i; if (hr >= H_) hr -= H_;
      const float* drow = dptr + hr * W_;
#pragma unroll
      for (int j = 0; j < 7; ++j) {
        int wc = gw + j; if (wc >= W_) wc -= W_;
        const float l = drow[wc] + rpb[head * KK_ + i * 7 + j];
        logit[i * 7 + j] = l;
        m = fmaxf(m, l);
      }
    }
    float s = 0.f;
#pragma unroll
    for (int o = 0; o < KK_; ++o) {
      const float e = __expf(logit[o] - m);
      s += e;
      at[o * 256 + tid] = e;
    }
    rsum[tid] = 1.0f / s;
  }
  __syncthreads();

  const int c4  = tid & 7;
  const int seg = tid >> 3;
  const int r   = seg >> 1;
  const int sx  = (seg & 1) * 8;
  const int gh  = r0 + r;
  const int pxb = r * 16 + sx;
  const float* vb = vbuf + (size_t)(b * NH_ + head) * HW_ * HD_ + c4 * 4;

  float4 acc[8];
#pragma unroll
  for (int xx = 0; xx < 8; ++xx) acc[xx] = make_float4(0.f, 0.f, 0.f, 0.f);

  for (int i = 0; i < 7; ++i) {
    int hr = gh + i; if (hr >= H_) hr -= H_;
    float4 win[14];
#pragma unroll
    for (int t = 0; t < 14; ++t) {
      int wc = w0 + sx + t; if (wc >= W_) wc -= W_;
      win[t] = *(const float4*)(vb + ((size_t)hr * W_ + wc) * HD_);
    }
#pragma unroll
    for (int j = 0; j < 7; ++j) {
      const float* arow = at + (i * 7 + j) * 256 + pxb;
      const float4 a0 = *(const float4*)arow;
      const float4 a1 = *(const float4*)(arow + 4);
      const float aw[8] = {a0.x, a0.y, a0.z, a0.w, a1.x, a1.y, a1.z, a1.w};
#pragma unroll
      for (int xx = 0; xx < 8; ++xx) {
        acc[xx].x = fmaf(aw[xx], win[xx + j].x, acc[xx].x);
        acc[xx].y = fmaf(aw[xx], win[xx + j].y, acc[xx].y);
        acc[xx].z = fmaf(aw[xx], win[xx + j].z, acc[xx].z);
        acc[xx].w = fmaf(aw[xx], win[xx + j].w, acc[xx].w);
      }
    }
  }

  float* op = abuf + ((size_t)b * HW_ + (size_t)gh * W_ + (w0 + sx)) * C_ + head * HD_ + c4 * 4;
#pragma unroll
  for (int xx = 0; xx < 8; ++xx) {
    const float rs = rsum[pxb + xx];
    *(float4*)(op + xx * C_) =
        make_float4(acc[xx].x * rs, acc[xx].y * rs, acc[xx].z * rs, acc[xx].w * rs);
  }
}

// ---------------- K3: proj GEMM + NHWC -> NCHW (unchanged) ----------------
__global__ __launch_bounds__(256) void k_proj(
    const float* __restrict__ abuf, const float* __restrict__ pwt,
    const float* __restrict__ pb, float* __restrict__ out)
{
  __shared__ float ys[64 * 129];
  const int tid = threadIdx.x;
  const int b   = blockIdx.x / 196;
  const int hw0 = (blockIdx.x % 196) * 64;
  {
    const float* ab = abuf + ((size_t)b * HW_ + hw0) * C_;
#pragma unroll
    for (int rep = 0; rep < 8; ++rep) {
      const int f4i = rep * 256 + tid;
      const int p  = f4i >> 5;
      const int cc = (f4i & 31) * 4;
      const float4 v = *(const float4*)(ab + p * C_ + cc);
      float* dst = ys + p * 129 + cc;
      dst[0] = v.x; dst[1] = v.y; dst[2] = v.z; dst[3] = v.w;
    }
  }
  __syncthreads();

  const int px = tid & 63;
  const int og = __builtin_amdgcn_readfirstlane((int)threadIdx.x >> 6);
  const float* yrow = ys + px * 129;
  const float* w = pwt + og * HD_;
  float acc[32];
#pragma unroll
  for (int t = 0; t < 32; ++t) acc[t] = pb[og * 32 + t];
#pragma unroll 2
  for (int c = 0; c < C_; ++c) {
    const float xv = yrow[c];
    const float* __restrict__ wr = w + c * C_;
#pragma unroll
    for (int t = 0; t < 32; ++t) acc[t] = fmaf(xv, wr[t], acc[t]);
  }
  float* o = out + (size_t)b * C_ * HW_ + (size_t)og * 32 * HW_ + hw0 + px;
#pragma unroll
  for (int t = 0; t < 32; ++t) o[(size_t)t * HW_] = acc[t];
}

extern "C" void kernel_launch(void* const* d_in, const int* in_sizes, int n_in,
                              void* d_out, int out_size, void* d_ws, size_t ws_size,
                              hipStream_t stream) {
  const float* x   = (const float*)d_in[0];
  const float* qw  = (const float*)d_in[1];
  const float* qb  = (const float*)d_in[2];
  const float* rpb = (const float*)d_in[3];
  const float* pw  = (const float*)d_in[4];
  const float* pb  = (const float*)d_in[5];
  float* out = (float*)d_out;

  float* vbuf = (float*)d_ws;                         // N_*C_ fp32 (51.4 MB)
  float* dotb = vbuf + (size_t)N_ * C_;               // N_*NH_ fp32 (1.6 MB)
  float* abuf = dotb + (size_t)N_ * NH_;              // N_*C_ fp32 (51.4 MB)
  float* pwt  = abuf + (size_t)N_ * C_;               // 128*128 fp32
  unsigned short* wh = (unsigned short*)(pwt + 128 * 128);  // 384*128 bf16
  unsigned short* wl = wh + 384 * 128;                      // 384*128 bf16

  hipLaunchKernelGGL(k_wt,   dim3(192), dim3(256), 0, stream, qw, pw, wh, wl, pwt);
  hipLaunchKernelGGL(k_qkv,  dim3(N_ / 64), dim3(256), 0, stream, x, wh, wl, qb, vbuf, dotb);
  hipLaunchKernelGGL(k_attn, dim3(NH_ * B_ * 49), dim3(256), 0, stream, vbuf, dotb, rpb, abuf);
  hipLaunchKernelGGL(k_proj, dim3(N_ / 64), dim3(256), 0, stream, abuf, pwt, pb, out);
}